// Round 8
// baseline (2525.832 us; speedup 1.0000x reference)
//
#include <hip/hip_runtime.h>
#include <hip/hip_bf16.h>

// Geometry (pad=1): conv1/conv2 -> (2,16,128^3), conv3 s2 -> (2,32,64^3).
// y1/y2 voxel-interleaved [b][z][y][x][ic16] (32B/voxel). f0 channel-major.
// Round 8: conv1 grid-stride kept, but unroll 1 + launch_bounds(256,4) to fix
// the VGPR 244 / occupancy 11.7% cliff (round-7 post-mortem).

typedef __hip_bfloat16 bf16;
typedef __attribute__((ext_vector_type(8))) short short8;   // 8 bf16 = 4 VGPR
typedef __attribute__((ext_vector_type(4))) float f32x4;
__device__ __forceinline__ float b2f(bf16 v){ return __bfloat162float(v); }
__device__ __forceinline__ bf16 f2b(float v){ return __float2bfloat16(v); }
__device__ __forceinline__ unsigned short f2bu(float f){   // RNE
  unsigned u = __float_as_uint(f);
  return (unsigned short)((u + 0x7fff + ((u>>16)&1)) >> 16);
}

#define SP12 2097152   // 128^3
#define SP3  262144    // 64^3
#define M_TOT 686
#define TOK_OFF 0
#define AUX_OFF 87808
#define CRD_OFF 109760
#define KSPLIT 32
#define NSLAB 32

// ---------------- conv1: (2,1,128^3)->(2,16,128^3) raw interleaved + stats --
// Grid-stride 16 voxels/thread; stats butterfly once per thread (LDS-pipe
// cost /16). unroll 1 + waves/EU>=4 keep VGPR <=128 (round-7 cliff fix).
__global__ __launch_bounds__(256, 4) void k_conv1(const float* __restrict__ x,
                                                  const float* __restrict__ w,
                                                  unsigned short* __restrict__ y1u,
                                                  float* __restrict__ psum1){
  __shared__ float wl[432];           // [oc16][27]
  __shared__ float red[128];
  int t = threadIdx.x;
  for(int i=t;i<432;i+=256) wl[i]=w[i];
  __syncthreads();
  float s[16], q[16];
#pragma unroll
  for(int c=0;c<16;c++){ s[c]=0.f; q[c]=0.f; }
  int base = blockIdx.x*256 + t;
#pragma unroll 1
  for(int it=0; it<16; it++){
    int tt = base + it*262144;
    int xx = tt & 127; int yy = (tt>>7)&127; int zz = (tt>>14)&127; int b = tt>>21;
    float acc[16];
#pragma unroll
    for(int o=0;o<16;o++) acc[o]=0.f;
    const float* xb = x + (size_t)b*SP12;
#pragma unroll
    for(int dz=0;dz<3;dz++){
      int iz = zz-1+dz; if((unsigned)iz >= 128u) continue;
#pragma unroll
      for(int dy=0;dy<3;dy++){
        int iy = yy-1+dy; if((unsigned)iy >= 128u) continue;
        const float* row = xb + iz*16384 + iy*128;
#pragma unroll
        for(int dx=0;dx<3;dx++){
          int ix = xx-1+dx; bool ok = (unsigned)ix < 128u;
          float v = row[ok?ix:0]; v = ok? v : 0.f;
          int wi = (dz*3+dy)*3+dx;
#pragma unroll
          for(int o=0;o<16;o++) acc[o] += v*wl[o*27+wi];
        }
      }
    }
    unsigned pk[8];
#pragma unroll
    for(int j=0;j<8;j++) pk[j] = (unsigned)f2bu(acc[2*j]) | ((unsigned)f2bu(acc[2*j+1])<<16);
    uint4 u0; u0.x=pk[0]; u0.y=pk[1]; u0.z=pk[2]; u0.w=pk[3];
    uint4 u1; u1.x=pk[4]; u1.y=pk[5]; u1.z=pk[6]; u1.w=pk[7];
    *(uint4*)(y1u + (size_t)tt*16)     = u0;
    *(uint4*)(y1u + (size_t)tt*16 + 8) = u1;
#pragma unroll
    for(int c=0;c<16;c++){ s[c] += acc[c]; q[c] += acc[c]*acc[c]; }
  }
  // one butterfly per channel, amortized over 16 voxels
  int lane = t & 63, wid = t>>6;
#pragma unroll
  for(int c=0;c<16;c++){
    float sv = s[c], qv = q[c];
#pragma unroll
    for(int off=32;off>0;off>>=1){ sv += __shfl_down(sv,off); qv += __shfl_down(qv,off); }
    if(lane==0){ red[wid*32+c]=sv; red[wid*32+16+c]=qv; }
  }
  __syncthreads();
  if(t<32){
    float tot = red[t]+red[32+t]+red[64+t]+red[96+t];
    atomicAdd(&psum1[(blockIdx.x & (NSLAB-1))*64 + t], tot);
  }
}

// ------------- scale/shift from slabbed sums --------------------------------
__global__ void k_finalize(const float* __restrict__ psum, const float* __restrict__ g,
                           const float* __restrict__ bb, float* __restrict__ scsh,
                           int C, float invN){
  int i = threadIdx.x;
  if(i<C){
    float s=0.f, q=0.f;
    for(int sl=0; sl<NSLAB; sl++){ s += psum[sl*64+i]; q += psum[sl*64+C+i]; }
    float mean = s*invN;
    float var  = q*invN - mean*mean;
    float sc = g[i]*rsqrtf(var+1e-5f);
    scsh[i]   = sc;
    scsh[C+i] = bb[i] - mean*sc;
  }
}

// ---------------- conv2 (MFMA): interleaved in/out, bn1+relu on stage -------
__global__ __launch_bounds__(256) void k_conv2(const unsigned short* __restrict__ y1u,
                                               const float* __restrict__ w,
                                               const float* __restrict__ scsh,
                                               unsigned short* __restrict__ y2u,
                                               float* __restrict__ psum2){
  __shared__ unsigned short tile[10*6*18*16];   // 34,560 B
  __shared__ unsigned short Wl[16*456];         // 14,592 B
  __shared__ float s_sc[16], s_sh[16];
  int t = threadIdx.x;
  if(t < 32){ float v = scsh[t]; if(t<16) s_sc[t]=v; else s_sh[t-16]=v; }
  for(int i=t;i<7168;i+=256){
    int oc = i/448; int k = i - oc*448;
    int tap = k>>4; int ic = k&15;
    float v = (tap<27)? w[(oc*16+ic)*27+tap] : 0.f;
    Wl[oc*456+k] = f2bu(v);
  }
  __syncthreads();
  int bx = blockIdx.x;
  int txx = bx&7, tyy=(bx>>3)&31, tzz=(bx>>8)&15, b=bx>>12;
  int x0 = txx*16, y0 = tyy*4, z0 = tzz*8;
  for(int i=t;i<2160;i+=256){
    int vox = i>>1, h = i&1;
    int xl_ = vox%18; int r1 = vox/18; int yy_ = r1%6; int zz_ = r1/6;
    int gx = x0+xl_-1, gy = y0+yy_-1, gz = z0+zz_-1;
    bool ok = ((unsigned)gx<128u)&&((unsigned)gy<128u)&&((unsigned)gz<128u);
    uint4 o; o.x=0;o.y=0;o.z=0;o.w=0;
    if(ok){
      uint4 u = *(const uint4*)(y1u + ((size_t)((b<<21)|(gz<<14)|(gy<<7)|gx))*16 + h*8);
      int c0 = h*8;
      unsigned uu[4]; uu[0]=u.x; uu[1]=u.y; uu[2]=u.z; uu[3]=u.w;
      unsigned oo[4];
#pragma unroll
      for(int j=0;j<4;j++){
        float lo = fmaxf(__uint_as_float(uu[j]<<16)        *s_sc[c0+2*j]   + s_sh[c0+2*j],   0.f);
        float hi = fmaxf(__uint_as_float(uu[j]&0xffff0000u)*s_sc[c0+2*j+1] + s_sh[c0+2*j+1], 0.f);
        oo[j] = (unsigned)f2bu(lo) | ((unsigned)f2bu(hi)<<16);
      }
      o.x=oo[0]; o.y=oo[1]; o.z=oo[2]; o.w=oo[3];
    }
    int sw = (xl_>>2)&1;
    *(uint4*)&tile[vox*16 + ((h^sw)*8)] = o;
  }
  __syncthreads();

  int lane = t & 63, wid = t>>6;
  int m = lane & 15, q = lane>>4;
  int qh = q&1, qt = q>>1;
  f32x4 acc[8];
#pragma unroll
  for(int r=0;r<8;r++) acc[r] = (f32x4){0.f,0.f,0.f,0.f};
  const char* tbase = (const char*)tile + wid*6912;
  const int woff = m*456;
#pragma unroll
  for(int kp=0;kp<14;kp++){
    short8 bfr = *(const short8*)&Wl[woff + kp*32 + q*8];
    int tap = kp*2 + qt; if(tap>26) tap=26;
    int dz = tap/9; int rr = tap - dz*9; int dy = rr/3; int dx = rr - dy*3;
    int xl = m + dx;
    int abyte = ((dz*6 + dy)*18 + xl)*32 + ((qh ^ ((xl>>2)&1))*16);
    const char* ap = tbase + abyte;
#pragma unroll
    for(int r=0;r<8;r++){
      const short8 af = *(const short8*)(ap + ((r>>2)*6 + (r&3))*576);
      acc[r] = __builtin_amdgcn_mfma_f32_16x16x32_bf16(af, bfr, acc[r], 0,0,0);
    }
  }
  float s=0.f, qv=0.f;
#pragma unroll
  for(int r=0;r<8;r++){
    int gz = z0 + wid*2 + (r>>2), gy = y0 + (r&3);
    size_t vbase = (size_t)((b<<21)|(gz<<14)|(gy<<7)) + x0 + q*4;
#pragma unroll
    for(int reg=0;reg<4;reg++){
      float v = acc[r][reg];
      s += v; qv += v*v;
      y2u[(vbase+reg)*16 + m] = f2bu(v);
    }
  }
  s  += __shfl_xor(s,16);  s  += __shfl_xor(s,32);
  qv += __shfl_xor(qv,16); qv += __shfl_xor(qv,32);
  __syncthreads();
  float* red = (float*)tile;
  if(lane<16){ red[wid*32+lane]=s; red[wid*32+16+lane]=qv; }
  __syncthreads();
  if(t<32){
    float tot = red[t]+red[32+t]+red[64+t]+red[96+t];
    atomicAdd(&psum2[(blockIdx.x & (NSLAB-1))*64 + t], tot);
  }
}

// ---------------- conv3 (MFMA, stride2): interleaved in, channel-major out --
__global__ __launch_bounds__(256) void k_conv3(const unsigned short* __restrict__ y2u,
                                               const float* __restrict__ w,
                                               const float* __restrict__ scsh,
                                               bf16* __restrict__ f0,
                                               float* __restrict__ psum3){
  __shared__ unsigned short tile3[5*9*33*16];   // 47,520 B
  __shared__ unsigned short Wl3[32*456];        // 29,184 B
  __shared__ float s_sc[16], s_sh[16];
  int t = threadIdx.x;
  if(t < 32){ float v = scsh[t]; if(t<16) s_sc[t]=v; else s_sh[t-16]=v; }
  for(int i=t;i<14336;i+=256){
    int oc = i/448; int k = i - oc*448;
    int tap = k>>4; int ic = k&15;
    float v = (tap<27)? w[(oc*16+ic)*27+tap] : 0.f;
    Wl3[oc*456+k] = f2bu(v);
  }
  __syncthreads();
  int bx = blockIdx.x;
  int tx = bx&3, ty=(bx>>2)&15, tz=(bx>>6)&31, b=bx>>11;
  int x0 = tx*16, y0 = ty*4, z0 = tz*2;
  int gx0 = 2*x0-1, gy0 = 2*y0-1, gz0 = 2*z0-1;
  for(int i=t;i<2970;i+=256){
    int vox = i>>1, h = i&1;
    int xl_ = vox%33; int r1 = vox/33; int yy_ = r1%9; int zz_ = r1/9;
    int gx = gx0+xl_, gy = gy0+yy_, gz = gz0+zz_;
    bool ok = (gx>=0)&&(gy>=0)&&(gz>=0);
    uint4 o; o.x=0;o.y=0;o.z=0;o.w=0;
    if(ok){
      uint4 u = *(const uint4*)(y2u + ((size_t)((b<<21)|(gz<<14)|(gy<<7)|gx))*16 + h*8);
      int c0 = h*8;
      unsigned uu[4]; uu[0]=u.x; uu[1]=u.y; uu[2]=u.z; uu[3]=u.w;
      unsigned oo[4];
#pragma unroll
      for(int j=0;j<4;j++){
        float lo = fmaxf(__uint_as_float(uu[j]<<16)        *s_sc[c0+2*j]   + s_sh[c0+2*j],   0.f);
        float hi = fmaxf(__uint_as_float(uu[j]&0xffff0000u)*s_sc[c0+2*j+1] + s_sh[c0+2*j+1], 0.f);
        oo[j] = (unsigned)f2bu(lo) | ((unsigned)f2bu(hi)<<16);
      }
      o.x=oo[0]; o.y=oo[1]; o.z=oo[2]; o.w=oo[3];
    }
    int sw = (xl_>>2)&1;
    *(uint4*)&tile3[vox*16 + ((h^sw)*8)] = o;
  }
  __syncthreads();

  int lane = t & 63, wid = t>>6;
  int m = lane & 15, q = lane>>4;
  int qh = q&1, qt = q>>1;
  f32x4 acc[2][2];
#pragma unroll
  for(int r=0;r<2;r++){ acc[r][0]=(f32x4){0,0,0,0}; acc[r][1]=(f32x4){0,0,0,0}; }
#pragma unroll
  for(int kp=0;kp<14;kp++){
    short8 bf0 = *(const short8*)&Wl3[ m     *456 + kp*32 + q*8];
    short8 bf1 = *(const short8*)&Wl3[(16+m)*456 + kp*32 + q*8];
    int tap = kp*2 + qt; if(tap>26) tap=26;
    int dz = tap/9; int rr = tap - dz*9; int dy = rr/3; int dx = rr - dy*3;
    int xl = 2*m + dx;
    int hb = (qh ^ ((xl>>2)&1))*16;
#pragma unroll
    for(int rl=0;rl<2;rl++){
      int row = wid*2 + rl;
      int tz_ = 2*(row>>2) + dz;
      int ty_ = 2*(row&3) + dy;
      const short8 af = *(const short8*)((const char*)tile3 + ((tz_*9+ty_)*33 + xl)*32 + hb);
      acc[rl][0] = __builtin_amdgcn_mfma_f32_16x16x32_bf16(af, bf0, acc[rl][0], 0,0,0);
      acc[rl][1] = __builtin_amdgcn_mfma_f32_16x16x32_bf16(af, bf1, acc[rl][1], 0,0,0);
    }
  }
  float s0=0.f,q0=0.f,s1=0.f,q1=0.f;
#pragma unroll
  for(int rl=0;rl<2;rl++){
    int row = wid*2 + rl;
    int oz = z0 + (row>>2), oy = y0 + (row&3);
    size_t sp = (size_t)oz*4096 + oy*64 + x0 + q*4;
#pragma unroll
    for(int oct=0;oct<2;oct++){
      int oc = oct*16 + m;
      bf16* dst = f0 + (size_t)(b*32+oc)*SP3 + sp;
#pragma unroll
      for(int reg=0;reg<4;reg++){
        float v = acc[rl][oct][reg];
        if(oct==0){ s0 += v; q0 += v*v; } else { s1 += v; q1 += v*v; }
        dst[reg] = f2b(v);
      }
    }
  }
  s0 += __shfl_xor(s0,16); s0 += __shfl_xor(s0,32);
  q0 += __shfl_xor(q0,16); q0 += __shfl_xor(q0,32);
  s1 += __shfl_xor(s1,16); s1 += __shfl_xor(s1,32);
  q1 += __shfl_xor(q1,16); q1 += __shfl_xor(q1,32);
  __syncthreads();
  float* red = (float*)tile3;
  if(lane<16){
    red[wid*64+lane]    = s0; red[wid*64+16+lane] = s1;
    red[wid*64+32+lane] = q0; red[wid*64+48+lane] = q1;
  }
  __syncthreads();
  if(t<64){
    float tot = red[t]+red[64+t]+red[128+t]+red[192+t];
    atomicAdd(&psum3[(blockIdx.x & (NSLAB-1))*64 + t], tot);
  }
}

// ---------------- W f32 -> bf16 pre-convert: wb[160][131072] ----------------
__global__ __launch_bounds__(256) void k_cvtw(const float* __restrict__ tokw,
                                              const float* __restrict__ auxw,
                                              unsigned short* __restrict__ wb){
  int i = blockIdx.x*256 + threadIdx.x;
  int n = i >> 15;
  int g = i & 32767;
  const float* src = (n<128)? tokw + (size_t)n*131072 : auxw + (size_t)(n-128)*131072;
  float4 v = *(const float4*)(src + g*4);
  ushort4 o; o.x=f2bu(v.x); o.y=f2bu(v.y); o.z=f2bu(v.z); o.w=f2bu(v.w);
  *(ushort4*)(wb + (size_t)n*131072 + g*4) = o;
}

// ---------------- MFMA projection GEMM: M=686, N=160, K=131072 --------------
__global__ __launch_bounds__(256) void k_gemm(const bf16* __restrict__ f0,
                                              const unsigned short* __restrict__ wb,
                                              const float* __restrict__ scsh3,
                                              float* __restrict__ out_acc){
  __shared__ unsigned short Al[64*72];
  __shared__ unsigned short Wl[160*72];
  int mblk = blockIdx.x % 11; int ks = blockIdx.x / 11;
  int M0 = mblk*64;
  int c  = ks;
  float sc = scsh3[c], sh = scsh3[32+c];
  int t = threadIdx.x;
  int lane = t & 63; int wid = t >> 6;
  int wm = (wid & 1)*32; int wn = (wid >> 1)*80;
  f32x4 acc[2][5];
#pragma unroll
  for(int i=0;i<2;i++)
#pragma unroll
    for(int j=0;j<5;j++) acc[i][j] = (f32x4){0.f,0.f,0.f,0.f};

  int ky_off0 = (t&7)>>1, half0 = t&1;
  int m_a = t>>3;
  int mg1 = M0 + m_a;       if(mg1>685) mg1=685;
  int mg2 = M0 + m_a + 32;  if(mg2>685) mg2=685;
  int b1 = mg1/343, r1 = mg1%343;
  int b2 = mg2/343, r2 = mg2%343;
  int sp1 = ((r1/49)*8)*4096 + (((r1/7)%7)*8)*64 + (r1%7)*8;
  int sp2 = ((r2/49)*8)*4096 + (((r2/7)%7)*8)*64 + (r2%7)*8;
  const bf16* f0c1 = f0 + (size_t)(b1*32+c)*SP3;
  const bf16* f0c2 = f0 + (size_t)(b2*32+c)*SP3;

  for(int bk=0; bk<64; bk++){
    int kz = bk>>2; int kyb = (bk&3)*4;
    __syncthreads();
#pragma unroll
    for(int p=0;p<5;p++){
      int n = p*32 + (t>>3);
      int koff = (t&7)*8;
      uint4 v = *(const uint4*)(wb + (size_t)n*131072 + ks*4096 + bk*64 + koff);
      *(uint4*)&Wl[n*72 + koff] = v;
    }
    {
      int ky = kyb + ky_off0; int xo = half0*8;
      int ldso = ky_off0*16 + half0*8;
      uint4 u1 = *(const uint4*)(f0c1 + sp1 + kz*4096 + ky*64 + xo);
      uint4 u2 = *(const uint4*)(f0c2 + sp2 + kz*4096 + ky*64 + xo);
      unsigned uu[8]; uu[0]=u1.x; uu[1]=u1.y; uu[2]=u1.z; uu[3]=u1.w;
      uu[4]=u2.x; uu[5]=u2.y; uu[6]=u2.z; uu[7]=u2.w;
      unsigned outw[8];
#pragma unroll
      for(int qq=0;qq<8;qq++){
        float lo = fmaxf(__uint_as_float(uu[qq]<<16)*sc + sh, 0.f);
        float hi = fmaxf(__uint_as_float(uu[qq]&0xffff0000u)*sc + sh, 0.f);
        outw[qq] = (unsigned)f2bu(lo) | ((unsigned)f2bu(hi)<<16);
      }
      uint4 w1; w1.x=outw[0]; w1.y=outw[1]; w1.z=outw[2]; w1.w=outw[3];
      uint4 w2; w2.x=outw[4]; w2.y=outw[5]; w2.z=outw[6]; w2.w=outw[7];
      *(uint4*)&Al[m_a*72 + ldso] = w1;
      *(uint4*)&Al[(m_a+32)*72 + ldso] = w2;
    }
    __syncthreads();
#pragma unroll
    for(int kstep=0;kstep<2;kstep++){
      int ko = kstep*32 + (lane>>4)*8;
      short8 af[2], bfr[5];
#pragma unroll
      for(int mt=0;mt<2;mt++)
        af[mt] = *(const short8*)&Al[(wm + mt*16 + (lane&15))*72 + ko];
#pragma unroll
      for(int nt=0;nt<5;nt++)
        bfr[nt] = *(const short8*)&Wl[(wn + nt*16 + (lane&15))*72 + ko];
#pragma unroll
      for(int mt=0;mt<2;mt++)
#pragma unroll
        for(int nt=0;nt<5;nt++)
          acc[mt][nt] = __builtin_amdgcn_mfma_f32_16x16x32_bf16(af[mt], bfr[nt], acc[mt][nt], 0,0,0);
    }
  }
#pragma unroll
  for(int mt=0;mt<2;mt++){
    int mb = M0 + wm + mt*16 + (lane>>4)*4;
#pragma unroll
    for(int nt=0;nt<5;nt++){
      int n = wn + nt*16 + (lane&15);
#pragma unroll
      for(int reg=0;reg<4;reg++){
        int mm = mb + reg;
        if(mm < M_TOT)
          out_acc[((size_t)ks*M_TOT + mm)*160 + n] = acc[mt][nt][reg];
      }
    }
  }
}

// ------------- reduce split-K, +bias, LN(tokens), coords, write out ---------
__global__ __launch_bounds__(256) void k_final(const float* __restrict__ out_acc,
                                               const float* __restrict__ tok_b,
                                               const float* __restrict__ aux_b,
                                               const float* __restrict__ ln_g,
                                               const float* __restrict__ ln_b,
                                               float* __restrict__ out){
  int m = blockIdx.x;            // 0..685
  int n = threadIdx.x;
  __shared__ float sA[128], sB[128];
  float sum = 0.f;
  if(n < 160){
    for(int ks=0;ks<KSPLIT;ks++) sum += out_acc[((size_t)ks*M_TOT+m)*160 + n];
  }
  float tval = 0.f;
  if(n < 128){
    tval = sum + tok_b[n];
    sA[n] = tval; sB[n] = tval*tval;
  }
  __syncthreads();
  for(int s=64;s>0;s>>=1){
    if(n < s){ sA[n] += sA[n+s]; sB[n] += sB[n+s]; }
    __syncthreads();
  }
  float mean = sA[0]*(1.f/128.f);
  float var  = sB[0]*(1.f/128.f) - mean*mean;
  float rstd = rsqrtf(var + 1e-5f);
  if(n<128){
    out[TOK_OFF + (size_t)m*128 + n] = (tval-mean)*rstd*ln_g[n] + ln_b[n];
  } else if(n<160){
    out[AUX_OFF + (size_t)m*32 + (n-128)] = sum + aux_b[n-128];
  } else if(n<163){
    int j = n-160;
    int pn = m % 343;
    int nz = pn/49, ny=(pn/7)%7, nx=pn%7;
    int g = (j==0)? nz : (j==1)? ny : nx;
    out[CRD_OFF + (size_t)m*3 + j] = (g*8 + 7.5f)*(1.f/63.f);
  }
}

extern "C" void kernel_launch(void* const* d_in, const int* in_sizes, int n_in,
                              void* d_out, int out_size, void* d_ws, size_t ws_size,
                              hipStream_t stream){
  const float* x    = (const float*)d_in[0];
  const float* w1   = (const float*)d_in[1];
  const float* g1   = (const float*)d_in[2];
  const float* b1   = (const float*)d_in[3];
  const float* w2   = (const float*)d_in[4];
  const float* g2   = (const float*)d_in[5];
  const float* b2   = (const float*)d_in[6];
  const float* w3   = (const float*)d_in[7];
  const float* g3   = (const float*)d_in[8];
  const float* b3   = (const float*)d_in[9];
  const float* tokw = (const float*)d_in[10];
  const float* tokb = (const float*)d_in[11];
  const float* auxw = (const float*)d_in[12];
  const float* auxb = (const float*)d_in[13];
  const float* lng  = (const float*)d_in[14];
  const float* lnb  = (const float*)d_in[15];
  float* out = (float*)d_out;

  // ws (256 MiB): y1 [0,128Mi) interleaved, y2 [128Mi,256Mi) interleaved.
  // After conv2, region0 reused: f0 [0,32Mi) channel-major,
  // out_acc [32Mi,+14.05MB), wbf [64Mi,+41.9MB). Stats scratch in d_out.
  char* ws = (char*)d_ws;
  unsigned short* y1u = (unsigned short*)ws;
  unsigned short* y2u = (unsigned short*)(ws + 134217728);
  bf16*  f0      = (bf16*)ws;
  float* out_acc = (float*)(ws + 33554432);
  unsigned short* wbf = (unsigned short*)(ws + 67108864);
  float* stats   = (float*)d_out;
  float* psum1 = stats;        float* psum2 = stats+2048; float* psum3 = stats+4096;
  float* scsh1 = stats+6144;   float* scsh2 = stats+6208; float* scsh3 = stats+6272;

  hipMemsetAsync(stats, 0, 6144*sizeof(float), stream);

  k_conv1<<<1024, 256, 0, stream>>>(x, w1, y1u, psum1);
  k_finalize<<<1, 64, 0, stream>>>(psum1, g1, b1, scsh1, 16, 1.f/4194304.f);
  k_conv2<<<8192, 256, 0, stream>>>(y1u, w2, scsh1, y2u, psum2);
  k_finalize<<<1, 64, 0, stream>>>(psum2, g2, b2, scsh2, 16, 1.f/4194304.f);
  k_conv3<<<4096, 256, 0, stream>>>(y2u, w3, scsh2, f0, psum3);
  k_finalize<<<1, 64, 0, stream>>>(psum3, g3, b3, scsh3, 32, 1.f/524288.f);
  k_cvtw<<<20480, 256, 0, stream>>>(tokw, auxw, wbf);
  k_gemm<<<352, 256, 0, stream>>>(f0, wbf, scsh3, out_acc);
  k_final<<<686, 256, 0, stream>>>(out_acc, tokb, auxb, lng, lnb, out);
}

// Round 9
// 789.795 us; speedup vs baseline: 3.1981x; 3.1981x over previous
//
#include <hip/hip_runtime.h>
#include <hip/hip_bf16.h>

// Geometry (pad=1): conv1/conv2 -> (2,16,128^3), conv3 s2 -> (2,32,64^3).
// y1/y2 voxel-interleaved [b][z][y][x][ic16] (32B/voxel). f0 channel-major.
// Round 9: conv1 un-fused (r8 spill disaster post-mortem): plain conv kernel
// (r6 body, 40 VGPR) + separate interleaved stats pass (50us HBM stream).

typedef __hip_bfloat16 bf16;
typedef __attribute__((ext_vector_type(8))) short short8;   // 8 bf16 = 4 VGPR
typedef __attribute__((ext_vector_type(4))) float f32x4;
__device__ __forceinline__ float b2f(bf16 v){ return __bfloat162float(v); }
__device__ __forceinline__ bf16 f2b(float v){ return __float2bfloat16(v); }
__device__ __forceinline__ unsigned short f2bu(float f){   // RNE
  unsigned u = __float_as_uint(f);
  return (unsigned short)((u + 0x7fff + ((u>>16)&1)) >> 16);
}

#define SP12 2097152   // 128^3
#define SP3  262144    // 64^3
#define M_TOT 686
#define TOK_OFF 0
#define AUX_OFF 87808
#define CRD_OFF 109760
#define KSPLIT 32
#define NSLAB 32

// ---------------- conv1: (2,1,128^3)->(2,16,128^3) raw interleaved ----------
__global__ __launch_bounds__(256) void k_conv1(const float* __restrict__ x,
                                               const float* __restrict__ w,
                                               unsigned short* __restrict__ y1u){
  __shared__ float wl[432];           // [oc16][27]
  int t = threadIdx.x;
  for(int i=t;i<432;i+=256) wl[i]=w[i];
  __syncthreads();
  int tt = blockIdx.x*256 + t;
  int xx = tt & 127; int yy = (tt>>7)&127; int zz = (tt>>14)&127; int b = tt>>21;
  float acc[16];
#pragma unroll
  for(int o=0;o<16;o++) acc[o]=0.f;
  const float* xb = x + (size_t)b*SP12;
#pragma unroll
  for(int dz=0;dz<3;dz++){
    int iz = zz-1+dz; if((unsigned)iz >= 128u) continue;
#pragma unroll
    for(int dy=0;dy<3;dy++){
      int iy = yy-1+dy; if((unsigned)iy >= 128u) continue;
      const float* row = xb + iz*16384 + iy*128;
#pragma unroll
      for(int dx=0;dx<3;dx++){
        int ix = xx-1+dx; bool ok = (unsigned)ix < 128u;
        float v = row[ok?ix:0]; v = ok? v : 0.f;
        int wi = (dz*3+dy)*3+dx;
#pragma unroll
        for(int o=0;o<16;o++) acc[o] += v*wl[o*27+wi];
      }
    }
  }
  unsigned pk[8];
#pragma unroll
  for(int j=0;j<8;j++) pk[j] = (unsigned)f2bu(acc[2*j]) | ((unsigned)f2bu(acc[2*j+1])<<16);
  uint4 u0; u0.x=pk[0]; u0.y=pk[1]; u0.z=pk[2]; u0.w=pk[3];
  uint4 u1; u1.x=pk[4]; u1.y=pk[5]; u1.z=pk[6]; u1.w=pk[7];
  *(uint4*)(y1u + (size_t)tt*16)     = u0;
  *(uint4*)(y1u + (size_t)tt*16 + 8) = u1;
}

// ------------- BN1 stats over interleaved y1: per-channel sum/sumsq ---------
// Thread parity <-> channel half (uint4 idx parity preserved: stride even).
// s[8]/q[8] in regs; one 80-shuffle butterfly per thread at the end.
__global__ __launch_bounds__(256) void k_stats1(const unsigned short* __restrict__ y1u,
                                                float* __restrict__ psum){
  const uint4* p = (const uint4*)y1u;           // 8,388,608 uint4 total
  int t = blockIdx.x*256 + threadIdx.x;
  float s[8], q[8];
#pragma unroll
  for(int j=0;j<8;j++){ s[j]=0.f; q[j]=0.f; }
  for(int i=t; i<8388608; i+=524288){           // stride even -> parity stable
    uint4 u = p[i];
    unsigned uu[4]; uu[0]=u.x; uu[1]=u.y; uu[2]=u.z; uu[3]=u.w;
#pragma unroll
    for(int j=0;j<4;j++){
      float lo = __uint_as_float(uu[j]<<16);
      float hi = __uint_as_float(uu[j]&0xffff0000u);
      s[2*j] += lo; q[2*j] += lo*lo;
      s[2*j+1] += hi; q[2*j+1] += hi*hi;
    }
  }
  // butterfly over same-parity lanes: xor 2,4,8,16,32
#pragma unroll
  for(int off=2; off<64; off<<=1){
#pragma unroll
    for(int j=0;j<8;j++){ s[j] += __shfl_xor(s[j],off); q[j] += __shfl_xor(q[j],off); }
  }
  int lane = threadIdx.x & 63;
  int half = t & 1;                              // channel base = half*8
  if(lane < 2){
    int slab = blockIdx.x & (NSLAB-1);
#pragma unroll
    for(int j=0;j<8;j++){
      atomicAdd(&psum[slab*64 + half*8 + j],      s[j]);
      atomicAdd(&psum[slab*64 + 16 + half*8 + j], q[j]);
    }
  }
}

// ------------- scale/shift from slabbed sums --------------------------------
__global__ void k_finalize(const float* __restrict__ psum, const float* __restrict__ g,
                           const float* __restrict__ bb, float* __restrict__ scsh,
                           int C, float invN){
  int i = threadIdx.x;
  if(i<C){
    float s=0.f, q=0.f;
    for(int sl=0; sl<NSLAB; sl++){ s += psum[sl*64+i]; q += psum[sl*64+C+i]; }
    float mean = s*invN;
    float var  = q*invN - mean*mean;
    float sc = g[i]*rsqrtf(var+1e-5f);
    scsh[i]   = sc;
    scsh[C+i] = bb[i] - mean*sc;
  }
}

// ---------------- conv2 (MFMA): interleaved in/out, bn1+relu on stage -------
__global__ __launch_bounds__(256) void k_conv2(const unsigned short* __restrict__ y1u,
                                               const float* __restrict__ w,
                                               const float* __restrict__ scsh,
                                               unsigned short* __restrict__ y2u,
                                               float* __restrict__ psum2){
  __shared__ unsigned short tile[10*6*18*16];   // 34,560 B
  __shared__ unsigned short Wl[16*456];         // 14,592 B
  __shared__ float s_sc[16], s_sh[16];
  int t = threadIdx.x;
  if(t < 32){ float v = scsh[t]; if(t<16) s_sc[t]=v; else s_sh[t-16]=v; }
  for(int i=t;i<7168;i+=256){
    int oc = i/448; int k = i - oc*448;
    int tap = k>>4; int ic = k&15;
    float v = (tap<27)? w[(oc*16+ic)*27+tap] : 0.f;
    Wl[oc*456+k] = f2bu(v);
  }
  __syncthreads();
  int bx = blockIdx.x;
  int txx = bx&7, tyy=(bx>>3)&31, tzz=(bx>>8)&15, b=bx>>12;
  int x0 = txx*16, y0 = tyy*4, z0 = tzz*8;
  for(int i=t;i<2160;i+=256){
    int vox = i>>1, h = i&1;
    int xl_ = vox%18; int r1 = vox/18; int yy_ = r1%6; int zz_ = r1/6;
    int gx = x0+xl_-1, gy = y0+yy_-1, gz = z0+zz_-1;
    bool ok = ((unsigned)gx<128u)&&((unsigned)gy<128u)&&((unsigned)gz<128u);
    uint4 o; o.x=0;o.y=0;o.z=0;o.w=0;
    if(ok){
      uint4 u = *(const uint4*)(y1u + ((size_t)((b<<21)|(gz<<14)|(gy<<7)|gx))*16 + h*8);
      int c0 = h*8;
      unsigned uu[4]; uu[0]=u.x; uu[1]=u.y; uu[2]=u.z; uu[3]=u.w;
      unsigned oo[4];
#pragma unroll
      for(int j=0;j<4;j++){
        float lo = fmaxf(__uint_as_float(uu[j]<<16)        *s_sc[c0+2*j]   + s_sh[c0+2*j],   0.f);
        float hi = fmaxf(__uint_as_float(uu[j]&0xffff0000u)*s_sc[c0+2*j+1] + s_sh[c0+2*j+1], 0.f);
        oo[j] = (unsigned)f2bu(lo) | ((unsigned)f2bu(hi)<<16);
      }
      o.x=oo[0]; o.y=oo[1]; o.z=oo[2]; o.w=oo[3];
    }
    int sw = (xl_>>2)&1;
    *(uint4*)&tile[vox*16 + ((h^sw)*8)] = o;
  }
  __syncthreads();

  int lane = t & 63, wid = t>>6;
  int m = lane & 15, q = lane>>4;
  int qh = q&1, qt = q>>1;
  f32x4 acc[8];
#pragma unroll
  for(int r=0;r<8;r++) acc[r] = (f32x4){0.f,0.f,0.f,0.f};
  const char* tbase = (const char*)tile + wid*6912;
  const int woff = m*456;
#pragma unroll
  for(int kp=0;kp<14;kp++){
    short8 bfr = *(const short8*)&Wl[woff + kp*32 + q*8];
    int tap = kp*2 + qt; if(tap>26) tap=26;
    int dz = tap/9; int rr = tap - dz*9; int dy = rr/3; int dx = rr - dy*3;
    int xl = m + dx;
    int abyte = ((dz*6 + dy)*18 + xl)*32 + ((qh ^ ((xl>>2)&1))*16);
    const char* ap = tbase + abyte;
#pragma unroll
    for(int r=0;r<8;r++){
      const short8 af = *(const short8*)(ap + ((r>>2)*6 + (r&3))*576);
      acc[r] = __builtin_amdgcn_mfma_f32_16x16x32_bf16(af, bfr, acc[r], 0,0,0);
    }
  }
  float s=0.f, qv=0.f;
#pragma unroll
  for(int r=0;r<8;r++){
    int gz = z0 + wid*2 + (r>>2), gy = y0 + (r&3);
    size_t vbase = (size_t)((b<<21)|(gz<<14)|(gy<<7)) + x0 + q*4;
#pragma unroll
    for(int reg=0;reg<4;reg++){
      float v = acc[r][reg];
      s += v; qv += v*v;
      y2u[(vbase+reg)*16 + m] = f2bu(v);
    }
  }
  s  += __shfl_xor(s,16);  s  += __shfl_xor(s,32);
  qv += __shfl_xor(qv,16); qv += __shfl_xor(qv,32);
  __syncthreads();
  float* red = (float*)tile;
  if(lane<16){ red[wid*32+lane]=s; red[wid*32+16+lane]=qv; }
  __syncthreads();
  if(t<32){
    float tot = red[t]+red[32+t]+red[64+t]+red[96+t];
    atomicAdd(&psum2[(blockIdx.x & (NSLAB-1))*64 + t], tot);
  }
}

// ---------------- conv3 (MFMA, stride2): interleaved in, channel-major out --
__global__ __launch_bounds__(256) void k_conv3(const unsigned short* __restrict__ y2u,
                                               const float* __restrict__ w,
                                               const float* __restrict__ scsh,
                                               bf16* __restrict__ f0,
                                               float* __restrict__ psum3){
  __shared__ unsigned short tile3[5*9*33*16];   // 47,520 B
  __shared__ unsigned short Wl3[32*456];        // 29,184 B
  __shared__ float s_sc[16], s_sh[16];
  int t = threadIdx.x;
  if(t < 32){ float v = scsh[t]; if(t<16) s_sc[t]=v; else s_sh[t-16]=v; }
  for(int i=t;i<14336;i+=256){
    int oc = i/448; int k = i - oc*448;
    int tap = k>>4; int ic = k&15;
    float v = (tap<27)? w[(oc*16+ic)*27+tap] : 0.f;
    Wl3[oc*456+k] = f2bu(v);
  }
  __syncthreads();
  int bx = blockIdx.x;
  int tx = bx&3, ty=(bx>>2)&15, tz=(bx>>6)&31, b=bx>>11;
  int x0 = tx*16, y0 = ty*4, z0 = tz*2;
  int gx0 = 2*x0-1, gy0 = 2*y0-1, gz0 = 2*z0-1;
  for(int i=t;i<2970;i+=256){
    int vox = i>>1, h = i&1;
    int xl_ = vox%33; int r1 = vox/33; int yy_ = r1%9; int zz_ = r1/9;
    int gx = gx0+xl_, gy = gy0+yy_, gz = gz0+zz_;
    bool ok = (gx>=0)&&(gy>=0)&&(gz>=0);
    uint4 o; o.x=0;o.y=0;o.z=0;o.w=0;
    if(ok){
      uint4 u = *(const uint4*)(y2u + ((size_t)((b<<21)|(gz<<14)|(gy<<7)|gx))*16 + h*8);
      int c0 = h*8;
      unsigned uu[4]; uu[0]=u.x; uu[1]=u.y; uu[2]=u.z; uu[3]=u.w;
      unsigned oo[4];
#pragma unroll
      for(int j=0;j<4;j++){
        float lo = fmaxf(__uint_as_float(uu[j]<<16)        *s_sc[c0+2*j]   + s_sh[c0+2*j],   0.f);
        float hi = fmaxf(__uint_as_float(uu[j]&0xffff0000u)*s_sc[c0+2*j+1] + s_sh[c0+2*j+1], 0.f);
        oo[j] = (unsigned)f2bu(lo) | ((unsigned)f2bu(hi)<<16);
      }
      o.x=oo[0]; o.y=oo[1]; o.z=oo[2]; o.w=oo[3];
    }
    int sw = (xl_>>2)&1;
    *(uint4*)&tile3[vox*16 + ((h^sw)*8)] = o;
  }
  __syncthreads();

  int lane = t & 63, wid = t>>6;
  int m = lane & 15, q = lane>>4;
  int qh = q&1, qt = q>>1;
  f32x4 acc[2][2];
#pragma unroll
  for(int r=0;r<2;r++){ acc[r][0]=(f32x4){0,0,0,0}; acc[r][1]=(f32x4){0,0,0,0}; }
#pragma unroll
  for(int kp=0;kp<14;kp++){
    short8 bf0 = *(const short8*)&Wl3[ m     *456 + kp*32 + q*8];
    short8 bf1 = *(const short8*)&Wl3[(16+m)*456 + kp*32 + q*8];
    int tap = kp*2 + qt; if(tap>26) tap=26;
    int dz = tap/9; int rr = tap - dz*9; int dy = rr/3; int dx = rr - dy*3;
    int xl = 2*m + dx;
    int hb = (qh ^ ((xl>>2)&1))*16;
#pragma unroll
    for(int rl=0;rl<2;rl++){
      int row = wid*2 + rl;
      int tz_ = 2*(row>>2) + dz;
      int ty_ = 2*(row&3) + dy;
      const short8 af = *(const short8*)((const char*)tile3 + ((tz_*9+ty_)*33 + xl)*32 + hb);
      acc[rl][0] = __builtin_amdgcn_mfma_f32_16x16x32_bf16(af, bf0, acc[rl][0], 0,0,0);
      acc[rl][1] = __builtin_amdgcn_mfma_f32_16x16x32_bf16(af, bf1, acc[rl][1], 0,0,0);
    }
  }
  float s0=0.f,q0=0.f,s1=0.f,q1=0.f;
#pragma unroll
  for(int rl=0;rl<2;rl++){
    int row = wid*2 + rl;
    int oz = z0 + (row>>2), oy = y0 + (row&3);
    size_t sp = (size_t)oz*4096 + oy*64 + x0 + q*4;
#pragma unroll
    for(int oct=0;oct<2;oct++){
      int oc = oct*16 + m;
      bf16* dst = f0 + (size_t)(b*32+oc)*SP3 + sp;
#pragma unroll
      for(int reg=0;reg<4;reg++){
        float v = acc[rl][oct][reg];
        if(oct==0){ s0 += v; q0 += v*v; } else { s1 += v; q1 += v*v; }
        dst[reg] = f2b(v);
      }
    }
  }
  s0 += __shfl_xor(s0,16); s0 += __shfl_xor(s0,32);
  q0 += __shfl_xor(q0,16); q0 += __shfl_xor(q0,32);
  s1 += __shfl_xor(s1,16); s1 += __shfl_xor(s1,32);
  q1 += __shfl_xor(q1,16); q1 += __shfl_xor(q1,32);
  __syncthreads();
  float* red = (float*)tile3;
  if(lane<16){
    red[wid*64+lane]    = s0; red[wid*64+16+lane] = s1;
    red[wid*64+32+lane] = q0; red[wid*64+48+lane] = q1;
  }
  __syncthreads();
  if(t<64){
    float tot = red[t]+red[64+t]+red[128+t]+red[192+t];
    atomicAdd(&psum3[(blockIdx.x & (NSLAB-1))*64 + t], tot);
  }
}

// ---------------- W f32 -> bf16 pre-convert: wb[160][131072] ----------------
__global__ __launch_bounds__(256) void k_cvtw(const float* __restrict__ tokw,
                                              const float* __restrict__ auxw,
                                              unsigned short* __restrict__ wb){
  int i = blockIdx.x*256 + threadIdx.x;
  int n = i >> 15;
  int g = i & 32767;
  const float* src = (n<128)? tokw + (size_t)n*131072 : auxw + (size_t)(n-128)*131072;
  float4 v = *(const float4*)(src + g*4);
  ushort4 o; o.x=f2bu(v.x); o.y=f2bu(v.y); o.z=f2bu(v.z); o.w=f2bu(v.w);
  *(ushort4*)(wb + (size_t)n*131072 + g*4) = o;
}

// ---------------- MFMA projection GEMM: M=686, N=160, K=131072 --------------
__global__ __launch_bounds__(256) void k_gemm(const bf16* __restrict__ f0,
                                              const unsigned short* __restrict__ wb,
                                              const float* __restrict__ scsh3,
                                              float* __restrict__ out_acc){
  __shared__ unsigned short Al[64*72];
  __shared__ unsigned short Wl[160*72];
  int mblk = blockIdx.x % 11; int ks = blockIdx.x / 11;
  int M0 = mblk*64;
  int c  = ks;
  float sc = scsh3[c], sh = scsh3[32+c];
  int t = threadIdx.x;
  int lane = t & 63; int wid = t >> 6;
  int wm = (wid & 1)*32; int wn = (wid >> 1)*80;
  f32x4 acc[2][5];
#pragma unroll
  for(int i=0;i<2;i++)
#pragma unroll
    for(int j=0;j<5;j++) acc[i][j] = (f32x4){0.f,0.f,0.f,0.f};

  int ky_off0 = (t&7)>>1, half0 = t&1;
  int m_a = t>>3;
  int mg1 = M0 + m_a;       if(mg1>685) mg1=685;
  int mg2 = M0 + m_a + 32;  if(mg2>685) mg2=685;
  int b1 = mg1/343, r1 = mg1%343;
  int b2 = mg2/343, r2 = mg2%343;
  int sp1 = ((r1/49)*8)*4096 + (((r1/7)%7)*8)*64 + (r1%7)*8;
  int sp2 = ((r2/49)*8)*4096 + (((r2/7)%7)*8)*64 + (r2%7)*8;
  const bf16* f0c1 = f0 + (size_t)(b1*32+c)*SP3;
  const bf16* f0c2 = f0 + (size_t)(b2*32+c)*SP3;

  for(int bk=0; bk<64; bk++){
    int kz = bk>>2; int kyb = (bk&3)*4;
    __syncthreads();
#pragma unroll
    for(int p=0;p<5;p++){
      int n = p*32 + (t>>3);
      int koff = (t&7)*8;
      uint4 v = *(const uint4*)(wb + (size_t)n*131072 + ks*4096 + bk*64 + koff);
      *(uint4*)&Wl[n*72 + koff] = v;
    }
    {
      int ky = kyb + ky_off0; int xo = half0*8;
      int ldso = ky_off0*16 + half0*8;
      uint4 u1 = *(const uint4*)(f0c1 + sp1 + kz*4096 + ky*64 + xo);
      uint4 u2 = *(const uint4*)(f0c2 + sp2 + kz*4096 + ky*64 + xo);
      unsigned uu[8]; uu[0]=u1.x; uu[1]=u1.y; uu[2]=u1.z; uu[3]=u1.w;
      uu[4]=u2.x; uu[5]=u2.y; uu[6]=u2.z; uu[7]=u2.w;
      unsigned outw[8];
#pragma unroll
      for(int qq=0;qq<8;qq++){
        float lo = fmaxf(__uint_as_float(uu[qq]<<16)*sc + sh, 0.f);
        float hi = fmaxf(__uint_as_float(uu[qq]&0xffff0000u)*sc + sh, 0.f);
        outw[qq] = (unsigned)f2bu(lo) | ((unsigned)f2bu(hi)<<16);
      }
      uint4 w1; w1.x=outw[0]; w1.y=outw[1]; w1.z=outw[2]; w1.w=outw[3];
      uint4 w2; w2.x=outw[4]; w2.y=outw[5]; w2.z=outw[6]; w2.w=outw[7];
      *(uint4*)&Al[m_a*72 + ldso] = w1;
      *(uint4*)&Al[(m_a+32)*72 + ldso] = w2;
    }
    __syncthreads();
#pragma unroll
    for(int kstep=0;kstep<2;kstep++){
      int ko = kstep*32 + (lane>>4)*8;
      short8 af[2], bfr[5];
#pragma unroll
      for(int mt=0;mt<2;mt++)
        af[mt] = *(const short8*)&Al[(wm + mt*16 + (lane&15))*72 + ko];
#pragma unroll
      for(int nt=0;nt<5;nt++)
        bfr[nt] = *(const short8*)&Wl[(wn + nt*16 + (lane&15))*72 + ko];
#pragma unroll
      for(int mt=0;mt<2;mt++)
#pragma unroll
        for(int nt=0;nt<5;nt++)
          acc[mt][nt] = __builtin_amdgcn_mfma_f32_16x16x32_bf16(af[mt], bfr[nt], acc[mt][nt], 0,0,0);
    }
  }
#pragma unroll
  for(int mt=0;mt<2;mt++){
    int mb = M0 + wm + mt*16 + (lane>>4)*4;
#pragma unroll
    for(int nt=0;nt<5;nt++){
      int n = wn + nt*16 + (lane&15);
#pragma unroll
      for(int reg=0;reg<4;reg++){
        int mm = mb + reg;
        if(mm < M_TOT)
          out_acc[((size_t)ks*M_TOT + mm)*160 + n] = acc[mt][nt][reg];
      }
    }
  }
}

// ------------- reduce split-K, +bias, LN(tokens), coords, write out ---------
__global__ __launch_bounds__(256) void k_final(const float* __restrict__ out_acc,
                                               const float* __restrict__ tok_b,
                                               const float* __restrict__ aux_b,
                                               const float* __restrict__ ln_g,
                                               const float* __restrict__ ln_b,
                                               float* __restrict__ out){
  int m = blockIdx.x;            // 0..685
  int n = threadIdx.x;
  __shared__ float sA[128], sB[128];
  float sum = 0.f;
  if(n < 160){
    for(int ks=0;ks<KSPLIT;ks++) sum += out_acc[((size_t)ks*M_TOT+m)*160 + n];
  }
  float tval = 0.f;
  if(n < 128){
    tval = sum + tok_b[n];
    sA[n] = tval; sB[n] = tval*tval;
  }
  __syncthreads();
  for(int s=64;s>0;s>>=1){
    if(n < s){ sA[n] += sA[n+s]; sB[n] += sB[n+s]; }
    __syncthreads();
  }
  float mean = sA[0]*(1.f/128.f);
  float var  = sB[0]*(1.f/128.f) - mean*mean;
  float rstd = rsqrtf(var + 1e-5f);
  if(n<128){
    out[TOK_OFF + (size_t)m*128 + n] = (tval-mean)*rstd*ln_g[n] + ln_b[n];
  } else if(n<160){
    out[AUX_OFF + (size_t)m*32 + (n-128)] = sum + aux_b[n-128];
  } else if(n<163){
    int j = n-160;
    int pn = m % 343;
    int nz = pn/49, ny=(pn/7)%7, nx=pn%7;
    int g = (j==0)? nz : (j==1)? ny : nx;
    out[CRD_OFF + (size_t)m*3 + j] = (g*8 + 7.5f)*(1.f/63.f);
  }
}

extern "C" void kernel_launch(void* const* d_in, const int* in_sizes, int n_in,
                              void* d_out, int out_size, void* d_ws, size_t ws_size,
                              hipStream_t stream){
  const float* x    = (const float*)d_in[0];
  const float* w1   = (const float*)d_in[1];
  const float* g1   = (const float*)d_in[2];
  const float* b1   = (const float*)d_in[3];
  const float* w2   = (const float*)d_in[4];
  const float* g2   = (const float*)d_in[5];
  const float* b2   = (const float*)d_in[6];
  const float* w3   = (const float*)d_in[7];
  const float* g3   = (const float*)d_in[8];
  const float* b3   = (const float*)d_in[9];
  const float* tokw = (const float*)d_in[10];
  const float* tokb = (const float*)d_in[11];
  const float* auxw = (const float*)d_in[12];
  const float* auxb = (const float*)d_in[13];
  const float* lng  = (const float*)d_in[14];
  const float* lnb  = (const float*)d_in[15];
  float* out = (float*)d_out;

  // ws (256 MiB): y1 [0,128Mi) interleaved, y2 [128Mi,256Mi) interleaved.
  // After conv2, region0 reused: f0 [0,32Mi) channel-major,
  // out_acc [32Mi,+14.05MB), wbf [64Mi,+41.9MB). Stats scratch in d_out.
  char* ws = (char*)d_ws;
  unsigned short* y1u = (unsigned short*)ws;
  unsigned short* y2u = (unsigned short*)(ws + 134217728);
  bf16*  f0      = (bf16*)ws;
  float* out_acc = (float*)(ws + 33554432);
  unsigned short* wbf = (unsigned short*)(ws + 67108864);
  float* stats   = (float*)d_out;
  float* psum1 = stats;        float* psum2 = stats+2048; float* psum3 = stats+4096;
  float* scsh1 = stats+6144;   float* scsh2 = stats+6208; float* scsh3 = stats+6272;

  hipMemsetAsync(stats, 0, 6144*sizeof(float), stream);

  k_conv1<<<16384, 256, 0, stream>>>(x, w1, y1u);
  k_stats1<<<2048, 256, 0, stream>>>(y1u, psum1);
  k_finalize<<<1, 64, 0, stream>>>(psum1, g1, b1, scsh1, 16, 1.f/4194304.f);
  k_conv2<<<8192, 256, 0, stream>>>(y1u, w2, scsh1, y2u, psum2);
  k_finalize<<<1, 64, 0, stream>>>(psum2, g2, b2, scsh2, 16, 1.f/4194304.f);
  k_conv3<<<4096, 256, 0, stream>>>(y2u, w3, scsh2, f0, psum3);
  k_finalize<<<1, 64, 0, stream>>>(psum3, g3, b3, scsh3, 32, 1.f/524288.f);
  k_cvtw<<<20480, 256, 0, stream>>>(tokw, auxw, wbf);
  k_gemm<<<352, 256, 0, stream>>>(f0, wbf, scsh3, out_acc);
  k_final<<<686, 256, 0, stream>>>(out_acc, tokb, auxb, lng, lnb, out);
}

// Round 10
// 629.461 us; speedup vs baseline: 4.0127x; 1.2547x over previous
//
#include <hip/hip_runtime.h>
#include <hip/hip_bf16.h>

// Geometry (pad=1): conv1/conv2 -> (2,16,128^3), conv3 s2 -> (2,32,64^3).
// y1/y2 voxel-interleaved [b][z][y][x][ic16] (32B/voxel). f0 channel-major.
// Round 10: LDS diet for MFMA convs — weights pre-packed to [oc][448] bf16 in
// global (k_packw, stored in d_out scratch) and read as B-frags via 16B global
// loads (L1-resident). conv3 LDS 77->48KB (2->3 blk/CU), conv2 49->35KB (3->4).

typedef __hip_bfloat16 bf16;
typedef __attribute__((ext_vector_type(8))) short short8;   // 8 bf16 = 4 VGPR
typedef __attribute__((ext_vector_type(4))) float f32x4;
__device__ __forceinline__ float b2f(bf16 v){ return __bfloat162float(v); }
__device__ __forceinline__ bf16 f2b(float v){ return __float2bfloat16(v); }
__device__ __forceinline__ unsigned short f2bu(float f){   // RNE
  unsigned u = __float_as_uint(f);
  return (unsigned short)((u + 0x7fff + ((u>>16)&1)) >> 16);
}

#define SP12 2097152   // 128^3
#define SP3  262144    // 64^3
#define M_TOT 686
#define TOK_OFF 0
#define AUX_OFF 87808
#define CRD_OFF 109760
#define KSPLIT 32
#define NSLAB 32

// ---------------- conv1: (2,1,128^3)->(2,16,128^3) raw interleaved ----------
__global__ __launch_bounds__(256) void k_conv1(const float* __restrict__ x,
                                               const float* __restrict__ w,
                                               unsigned short* __restrict__ y1u){
  __shared__ float wl[432];           // [oc16][27]
  int t = threadIdx.x;
  for(int i=t;i<432;i+=256) wl[i]=w[i];
  __syncthreads();
  int tt = blockIdx.x*256 + t;
  int xx = tt & 127; int yy = (tt>>7)&127; int zz = (tt>>14)&127; int b = tt>>21;
  float acc[16];
#pragma unroll
  for(int o=0;o<16;o++) acc[o]=0.f;
  const float* xb = x + (size_t)b*SP12;
#pragma unroll
  for(int dz=0;dz<3;dz++){
    int iz = zz-1+dz; if((unsigned)iz >= 128u) continue;
#pragma unroll
    for(int dy=0;dy<3;dy++){
      int iy = yy-1+dy; if((unsigned)iy >= 128u) continue;
      const float* row = xb + iz*16384 + iy*128;
#pragma unroll
      for(int dx=0;dx<3;dx++){
        int ix = xx-1+dx; bool ok = (unsigned)ix < 128u;
        float v = row[ok?ix:0]; v = ok? v : 0.f;
        int wi = (dz*3+dy)*3+dx;
#pragma unroll
        for(int o=0;o<16;o++) acc[o] += v*wl[o*27+wi];
      }
    }
  }
  unsigned pk[8];
#pragma unroll
  for(int j=0;j<8;j++) pk[j] = (unsigned)f2bu(acc[2*j]) | ((unsigned)f2bu(acc[2*j+1])<<16);
  uint4 u0; u0.x=pk[0]; u0.y=pk[1]; u0.z=pk[2]; u0.w=pk[3];
  uint4 u1; u1.x=pk[4]; u1.y=pk[5]; u1.z=pk[6]; u1.w=pk[7];
  *(uint4*)(y1u + (size_t)tt*16)     = u0;
  *(uint4*)(y1u + (size_t)tt*16 + 8) = u1;
}

// ------------- BN1 stats over interleaved y1: per-channel sum/sumsq ---------
__global__ __launch_bounds__(256) void k_stats1(const unsigned short* __restrict__ y1u,
                                                float* __restrict__ psum){
  const uint4* p = (const uint4*)y1u;           // 8,388,608 uint4 total
  int t = blockIdx.x*256 + threadIdx.x;
  float s[8], q[8];
#pragma unroll
  for(int j=0;j<8;j++){ s[j]=0.f; q[j]=0.f; }
  for(int i=t; i<8388608; i+=524288){           // stride even -> parity stable
    uint4 u = p[i];
    unsigned uu[4]; uu[0]=u.x; uu[1]=u.y; uu[2]=u.z; uu[3]=u.w;
#pragma unroll
    for(int j=0;j<4;j++){
      float lo = __uint_as_float(uu[j]<<16);
      float hi = __uint_as_float(uu[j]&0xffff0000u);
      s[2*j] += lo; q[2*j] += lo*lo;
      s[2*j+1] += hi; q[2*j+1] += hi*hi;
    }
  }
#pragma unroll
  for(int off=2; off<64; off<<=1){
#pragma unroll
    for(int j=0;j<8;j++){ s[j] += __shfl_xor(s[j],off); q[j] += __shfl_xor(q[j],off); }
  }
  int lane = threadIdx.x & 63;
  int half = t & 1;                              // channel base = half*8
  if(lane < 2){
    int slab = blockIdx.x & (NSLAB-1);
#pragma unroll
    for(int j=0;j<8;j++){
      atomicAdd(&psum[slab*64 + half*8 + j],      s[j]);
      atomicAdd(&psum[slab*64 + 16 + half*8 + j], q[j]);
    }
  }
}

// ------------- scale/shift from slabbed sums --------------------------------
__global__ void k_finalize(const float* __restrict__ psum, const float* __restrict__ g,
                           const float* __restrict__ bb, float* __restrict__ scsh,
                           int C, float invN){
  int i = threadIdx.x;
  if(i<C){
    float s=0.f, q=0.f;
    for(int sl=0; sl<NSLAB; sl++){ s += psum[sl*64+i]; q += psum[sl*64+C+i]; }
    float mean = s*invN;
    float var  = q*invN - mean*mean;
    float sc = g[i]*rsqrtf(var+1e-5f);
    scsh[i]   = sc;
    scsh[C+i] = bb[i] - mean*sc;
  }
}

// ------------- pack conv weights to B-frag layout [oc][448], tap27=0 --------
__global__ __launch_bounds__(256) void k_packw(const float* __restrict__ w2,
                                               const float* __restrict__ w3,
                                               unsigned short* __restrict__ wp2,
                                               unsigned short* __restrict__ wp3){
  int i = blockIdx.x*256 + threadIdx.x;   // 21504 items
  if(i < 7168){
    int oc = i/448, k = i - oc*448;
    int tap = k>>4, ic = k&15;
    float v = (tap<27)? w2[(oc*16+ic)*27+tap] : 0.f;
    wp2[oc*448+k] = f2bu(v);
  } else if(i < 21504){
    int j = i - 7168;
    int oc = j/448, k = j - oc*448;
    int tap = k>>4, ic = k&15;
    float v = (tap<27)? w3[(oc*16+ic)*27+tap] : 0.f;
    wp3[oc*448+k] = f2bu(v);
  }
}

// ---------------- conv2 (MFMA): interleaved in/out, bn1+relu on stage -------
// Weights via 16B global loads from wp2 (L1-resident 14KB). LDS = tile only.
__global__ __launch_bounds__(256) void k_conv2(const unsigned short* __restrict__ y1u,
                                               const unsigned short* __restrict__ wp2,
                                               const float* __restrict__ scsh,
                                               unsigned short* __restrict__ y2u,
                                               float* __restrict__ psum2){
  __shared__ unsigned short tile[10*6*18*16];   // 34,560 B
  __shared__ float s_sc[16], s_sh[16];
  int t = threadIdx.x;
  if(t < 32){ float v = scsh[t]; if(t<16) s_sc[t]=v; else s_sh[t-16]=v; }
  __syncthreads();
  int bx = blockIdx.x;
  int txx = bx&7, tyy=(bx>>3)&31, tzz=(bx>>8)&15, b=bx>>12;
  int x0 = txx*16, y0 = tyy*4, z0 = tzz*8;
  for(int i=t;i<2160;i+=256){
    int vox = i>>1, h = i&1;
    int xl_ = vox%18; int r1 = vox/18; int yy_ = r1%6; int zz_ = r1/6;
    int gx = x0+xl_-1, gy = y0+yy_-1, gz = z0+zz_-1;
    bool ok = ((unsigned)gx<128u)&&((unsigned)gy<128u)&&((unsigned)gz<128u);
    uint4 o; o.x=0;o.y=0;o.z=0;o.w=0;
    if(ok){
      uint4 u = *(const uint4*)(y1u + ((size_t)((b<<21)|(gz<<14)|(gy<<7)|gx))*16 + h*8);
      int c0 = h*8;
      unsigned uu[4]; uu[0]=u.x; uu[1]=u.y; uu[2]=u.z; uu[3]=u.w;
      unsigned oo[4];
#pragma unroll
      for(int j=0;j<4;j++){
        float lo = fmaxf(__uint_as_float(uu[j]<<16)        *s_sc[c0+2*j]   + s_sh[c0+2*j],   0.f);
        float hi = fmaxf(__uint_as_float(uu[j]&0xffff0000u)*s_sc[c0+2*j+1] + s_sh[c0+2*j+1], 0.f);
        oo[j] = (unsigned)f2bu(lo) | ((unsigned)f2bu(hi)<<16);
      }
      o.x=oo[0]; o.y=oo[1]; o.z=oo[2]; o.w=oo[3];
    }
    int sw = (xl_>>2)&1;
    *(uint4*)&tile[vox*16 + ((h^sw)*8)] = o;
  }
  __syncthreads();

  int lane = t & 63, wid = t>>6;
  int m = lane & 15, q = lane>>4;
  int qh = q&1, qt = q>>1;
  f32x4 acc[8];
#pragma unroll
  for(int r=0;r<8;r++) acc[r] = (f32x4){0.f,0.f,0.f,0.f};
  const char* tbase = (const char*)tile + wid*6912;
  const unsigned short* wrow = wp2 + m*448 + q*8;
#pragma unroll
  for(int kp=0;kp<14;kp++){
    short8 bfr = *(const short8*)(wrow + kp*32);
    int tap = kp*2 + qt; if(tap>26) tap=26;
    int dz = tap/9; int rr = tap - dz*9; int dy = rr/3; int dx = rr - dy*3;
    int xl = m + dx;
    int abyte = ((dz*6 + dy)*18 + xl)*32 + ((qh ^ ((xl>>2)&1))*16);
    const char* ap = tbase + abyte;
#pragma unroll
    for(int r=0;r<8;r++){
      const short8 af = *(const short8*)(ap + ((r>>2)*6 + (r&3))*576);
      acc[r] = __builtin_amdgcn_mfma_f32_16x16x32_bf16(af, bfr, acc[r], 0,0,0);
    }
  }
  float s=0.f, qv=0.f;
#pragma unroll
  for(int r=0;r<8;r++){
    int gz = z0 + wid*2 + (r>>2), gy = y0 + (r&3);
    size_t vbase = (size_t)((b<<21)|(gz<<14)|(gy<<7)) + x0 + q*4;
#pragma unroll
    for(int reg=0;reg<4;reg++){
      float v = acc[r][reg];
      s += v; qv += v*v;
      y2u[(vbase+reg)*16 + m] = f2bu(v);
    }
  }
  s  += __shfl_xor(s,16);  s  += __shfl_xor(s,32);
  qv += __shfl_xor(qv,16); qv += __shfl_xor(qv,32);
  __syncthreads();
  float* red = (float*)tile;
  if(lane<16){ red[wid*32+lane]=s; red[wid*32+16+lane]=qv; }
  __syncthreads();
  if(t<32){
    float tot = red[t]+red[32+t]+red[64+t]+red[96+t];
    atomicAdd(&psum2[(blockIdx.x & (NSLAB-1))*64 + t], tot);
  }
}

// ---------------- conv3 (MFMA, stride2): interleaved in, channel-major out --
// Weights via 16B global loads from wp3 (L1-resident 28KB). LDS = tile only.
__global__ __launch_bounds__(256) void k_conv3(const unsigned short* __restrict__ y2u,
                                               const unsigned short* __restrict__ wp3,
                                               const float* __restrict__ scsh,
                                               bf16* __restrict__ f0,
                                               float* __restrict__ psum3){
  __shared__ unsigned short tile3[5*9*33*16];   // 47,520 B
  __shared__ float s_sc[16], s_sh[16];
  int t = threadIdx.x;
  if(t < 32){ float v = scsh[t]; if(t<16) s_sc[t]=v; else s_sh[t-16]=v; }
  __syncthreads();
  int bx = blockIdx.x;
  int tx = bx&3, ty=(bx>>2)&15, tz=(bx>>6)&31, b=bx>>11;
  int x0 = tx*16, y0 = ty*4, z0 = tz*2;
  int gx0 = 2*x0-1, gy0 = 2*y0-1, gz0 = 2*z0-1;
  for(int i=t;i<2970;i+=256){
    int vox = i>>1, h = i&1;
    int xl_ = vox%33; int r1 = vox/33; int yy_ = r1%9; int zz_ = r1/9;
    int gx = gx0+xl_, gy = gy0+yy_, gz = gz0+zz_;
    bool ok = (gx>=0)&&(gy>=0)&&(gz>=0);
    uint4 o; o.x=0;o.y=0;o.z=0;o.w=0;
    if(ok){
      uint4 u = *(const uint4*)(y2u + ((size_t)((b<<21)|(gz<<14)|(gy<<7)|gx))*16 + h*8);
      int c0 = h*8;
      unsigned uu[4]; uu[0]=u.x; uu[1]=u.y; uu[2]=u.z; uu[3]=u.w;
      unsigned oo[4];
#pragma unroll
      for(int j=0;j<4;j++){
        float lo = fmaxf(__uint_as_float(uu[j]<<16)        *s_sc[c0+2*j]   + s_sh[c0+2*j],   0.f);
        float hi = fmaxf(__uint_as_float(uu[j]&0xffff0000u)*s_sc[c0+2*j+1] + s_sh[c0+2*j+1], 0.f);
        oo[j] = (unsigned)f2bu(lo) | ((unsigned)f2bu(hi)<<16);
      }
      o.x=oo[0]; o.y=oo[1]; o.z=oo[2]; o.w=oo[3];
    }
    int sw = (xl_>>2)&1;
    *(uint4*)&tile3[vox*16 + ((h^sw)*8)] = o;
  }
  __syncthreads();

  int lane = t & 63, wid = t>>6;
  int m = lane & 15, q = lane>>4;
  int qh = q&1, qt = q>>1;
  f32x4 acc[2][2];
#pragma unroll
  for(int r=0;r<2;r++){ acc[r][0]=(f32x4){0,0,0,0}; acc[r][1]=(f32x4){0,0,0,0}; }
  const unsigned short* wrow0 = wp3 + m*448 + q*8;
  const unsigned short* wrow1 = wp3 + (16+m)*448 + q*8;
#pragma unroll
  for(int kp=0;kp<14;kp++){
    short8 bf0 = *(const short8*)(wrow0 + kp*32);
    short8 bf1 = *(const short8*)(wrow1 + kp*32);
    int tap = kp*2 + qt; if(tap>26) tap=26;
    int dz = tap/9; int rr = tap - dz*9; int dy = rr/3; int dx = rr - dy*3;
    int xl = 2*m + dx;
    int hb = (qh ^ ((xl>>2)&1))*16;
#pragma unroll
    for(int rl=0;rl<2;rl++){
      int row = wid*2 + rl;
      int tz_ = 2*(row>>2) + dz;
      int ty_ = 2*(row&3) + dy;
      const short8 af = *(const short8*)((const char*)tile3 + ((tz_*9+ty_)*33 + xl)*32 + hb);
      acc[rl][0] = __builtin_amdgcn_mfma_f32_16x16x32_bf16(af, bf0, acc[rl][0], 0,0,0);
      acc[rl][1] = __builtin_amdgcn_mfma_f32_16x16x32_bf16(af, bf1, acc[rl][1], 0,0,0);
    }
  }
  float s0=0.f,q0=0.f,s1=0.f,q1=0.f;
#pragma unroll
  for(int rl=0;rl<2;rl++){
    int row = wid*2 + rl;
    int oz = z0 + (row>>2), oy = y0 + (row&3);
    size_t sp = (size_t)oz*4096 + oy*64 + x0 + q*4;
#pragma unroll
    for(int oct=0;oct<2;oct++){
      int oc = oct*16 + m;
      bf16* dst = f0 + (size_t)(b*32+oc)*SP3 + sp;
#pragma unroll
      for(int reg=0;reg<4;reg++){
        float v = acc[rl][oct][reg];
        if(oct==0){ s0 += v; q0 += v*v; } else { s1 += v; q1 += v*v; }
        dst[reg] = f2b(v);
      }
    }
  }
  s0 += __shfl_xor(s0,16); s0 += __shfl_xor(s0,32);
  q0 += __shfl_xor(q0,16); q0 += __shfl_xor(q0,32);
  s1 += __shfl_xor(s1,16); s1 += __shfl_xor(s1,32);
  q1 += __shfl_xor(q1,16); q1 += __shfl_xor(q1,32);
  __syncthreads();
  float* red = (float*)tile3;
  if(lane<16){
    red[wid*64+lane]    = s0; red[wid*64+16+lane] = s1;
    red[wid*64+32+lane] = q0; red[wid*64+48+lane] = q1;
  }
  __syncthreads();
  if(t<64){
    float tot = red[t]+red[64+t]+red[128+t]+red[192+t];
    atomicAdd(&psum3[(blockIdx.x & (NSLAB-1))*64 + t], tot);
  }
}

// ---------------- W f32 -> bf16 pre-convert: wb[160][131072] ----------------
__global__ __launch_bounds__(256) void k_cvtw(const float* __restrict__ tokw,
                                              const float* __restrict__ auxw,
                                              unsigned short* __restrict__ wb){
  int i = blockIdx.x*256 + threadIdx.x;
  int n = i >> 15;
  int g = i & 32767;
  const float* src = (n<128)? tokw + (size_t)n*131072 : auxw + (size_t)(n-128)*131072;
  float4 v = *(const float4*)(src + g*4);
  ushort4 o; o.x=f2bu(v.x); o.y=f2bu(v.y); o.z=f2bu(v.z); o.w=f2bu(v.w);
  *(ushort4*)(wb + (size_t)n*131072 + g*4) = o;
}

// ---------------- MFMA projection GEMM: M=686, N=160, K=131072 --------------
__global__ __launch_bounds__(256) void k_gemm(const bf16* __restrict__ f0,
                                              const unsigned short* __restrict__ wb,
                                              const float* __restrict__ scsh3,
                                              float* __restrict__ out_acc){
  __shared__ unsigned short Al[64*72];
  __shared__ unsigned short Wl[160*72];
  int mblk = blockIdx.x % 11; int ks = blockIdx.x / 11;
  int M0 = mblk*64;
  int c  = ks;
  float sc = scsh3[c], sh = scsh3[32+c];
  int t = threadIdx.x;
  int lane = t & 63; int wid = t >> 6;
  int wm = (wid & 1)*32; int wn = (wid >> 1)*80;
  f32x4 acc[2][5];
#pragma unroll
  for(int i=0;i<2;i++)
#pragma unroll
    for(int j=0;j<5;j++) acc[i][j] = (f32x4){0.f,0.f,0.f,0.f};

  int ky_off0 = (t&7)>>1, half0 = t&1;
  int m_a = t>>3;
  int mg1 = M0 + m_a;       if(mg1>685) mg1=685;
  int mg2 = M0 + m_a + 32;  if(mg2>685) mg2=685;
  int b1 = mg1/343, r1 = mg1%343;
  int b2 = mg2/343, r2 = mg2%343;
  int sp1 = ((r1/49)*8)*4096 + (((r1/7)%7)*8)*64 + (r1%7)*8;
  int sp2 = ((r2/49)*8)*4096 + (((r2/7)%7)*8)*64 + (r2%7)*8;
  const bf16* f0c1 = f0 + (size_t)(b1*32+c)*SP3;
  const bf16* f0c2 = f0 + (size_t)(b2*32+c)*SP3;

  for(int bk=0; bk<64; bk++){
    int kz = bk>>2; int kyb = (bk&3)*4;
    __syncthreads();
#pragma unroll
    for(int p=0;p<5;p++){
      int n = p*32 + (t>>3);
      int koff = (t&7)*8;
      uint4 v = *(const uint4*)(wb + (size_t)n*131072 + ks*4096 + bk*64 + koff);
      *(uint4*)&Wl[n*72 + koff] = v;
    }
    {
      int ky = kyb + ky_off0; int xo = half0*8;
      int ldso = ky_off0*16 + half0*8;
      uint4 u1 = *(const uint4*)(f0c1 + sp1 + kz*4096 + ky*64 + xo);
      uint4 u2 = *(const uint4*)(f0c2 + sp2 + kz*4096 + ky*64 + xo);
      unsigned uu[8]; uu[0]=u1.x; uu[1]=u1.y; uu[2]=u1.z; uu[3]=u1.w;
      uu[4]=u2.x; uu[5]=u2.y; uu[6]=u2.z; uu[7]=u2.w;
      unsigned outw[8];
#pragma unroll
      for(int qq=0;qq<8;qq++){
        float lo = fmaxf(__uint_as_float(uu[qq]<<16)*sc + sh, 0.f);
        float hi = fmaxf(__uint_as_float(uu[qq]&0xffff0000u)*sc + sh, 0.f);
        outw[qq] = (unsigned)f2bu(lo) | ((unsigned)f2bu(hi)<<16);
      }
      uint4 w1; w1.x=outw[0]; w1.y=outw[1]; w1.z=outw[2]; w1.w=outw[3];
      uint4 w2; w2.x=outw[4]; w2.y=outw[5]; w2.z=outw[6]; w2.w=outw[7];
      *(uint4*)&Al[m_a*72 + ldso] = w1;
      *(uint4*)&Al[(m_a+32)*72 + ldso] = w2;
    }
    __syncthreads();
#pragma unroll
    for(int kstep=0;kstep<2;kstep++){
      int ko = kstep*32 + (lane>>4)*8;
      short8 af[2], bfr[5];
#pragma unroll
      for(int mt=0;mt<2;mt++)
        af[mt] = *(const short8*)&Al[(wm + mt*16 + (lane&15))*72 + ko];
#pragma unroll
      for(int nt=0;nt<5;nt++)
        bfr[nt] = *(const short8*)&Wl[(wn + nt*16 + (lane&15))*72 + ko];
#pragma unroll
      for(int mt=0;mt<2;mt++)
#pragma unroll
        for(int nt=0;nt<5;nt++)
          acc[mt][nt] = __builtin_amdgcn_mfma_f32_16x16x32_bf16(af[mt], bfr[nt], acc[mt][nt], 0,0,0);
    }
  }
#pragma unroll
  for(int mt=0;mt<2;mt++){
    int mb = M0 + wm + mt*16 + (lane>>4)*4;
#pragma unroll
    for(int nt=0;nt<5;nt++){
      int n = wn + nt*16 + (lane&15);
#pragma unroll
      for(int reg=0;reg<4;reg++){
        int mm = mb + reg;
        if(mm < M_TOT)
          out_acc[((size_t)ks*M_TOT + mm)*160 + n] = acc[mt][nt][reg];
      }
    }
  }
}

// ------------- reduce split-K, +bias, LN(tokens), coords, write out ---------
__global__ __launch_bounds__(256) void k_final(const float* __restrict__ out_acc,
                                               const float* __restrict__ tok_b,
                                               const float* __restrict__ aux_b,
                                               const float* __restrict__ ln_g,
                                               const float* __restrict__ ln_b,
                                               float* __restrict__ out){
  int m = blockIdx.x;            // 0..685
  int n = threadIdx.x;
  __shared__ float sA[128], sB[128];
  float sum = 0.f;
  if(n < 160){
    for(int ks=0;ks<KSPLIT;ks++) sum += out_acc[((size_t)ks*M_TOT+m)*160 + n];
  }
  float tval = 0.f;
  if(n < 128){
    tval = sum + tok_b[n];
    sA[n] = tval; sB[n] = tval*tval;
  }
  __syncthreads();
  for(int s=64;s>0;s>>=1){
    if(n < s){ sA[n] += sA[n+s]; sB[n] += sB[n+s]; }
    __syncthreads();
  }
  float mean = sA[0]*(1.f/128.f);
  float var  = sB[0]*(1.f/128.f) - mean*mean;
  float rstd = rsqrtf(var + 1e-5f);
  if(n<128){
    out[TOK_OFF + (size_t)m*128 + n] = (tval-mean)*rstd*ln_g[n] + ln_b[n];
  } else if(n<160){
    out[AUX_OFF + (size_t)m*32 + (n-128)] = sum + aux_b[n-128];
  } else if(n<163){
    int j = n-160;
    int pn = m % 343;
    int nz = pn/49, ny=(pn/7)%7, nx=pn%7;
    int g = (j==0)? nz : (j==1)? ny : nx;
    out[CRD_OFF + (size_t)m*3 + j] = (g*8 + 7.5f)*(1.f/63.f);
  }
}

extern "C" void kernel_launch(void* const* d_in, const int* in_sizes, int n_in,
                              void* d_out, int out_size, void* d_ws, size_t ws_size,
                              hipStream_t stream){
  const float* x    = (const float*)d_in[0];
  const float* w1   = (const float*)d_in[1];
  const float* g1   = (const float*)d_in[2];
  const float* b1   = (const float*)d_in[3];
  const float* w2   = (const float*)d_in[4];
  const float* g2   = (const float*)d_in[5];
  const float* b2   = (const float*)d_in[6];
  const float* w3   = (const float*)d_in[7];
  const float* g3   = (const float*)d_in[8];
  const float* b3   = (const float*)d_in[9];
  const float* tokw = (const float*)d_in[10];
  const float* tokb = (const float*)d_in[11];
  const float* auxw = (const float*)d_in[12];
  const float* auxb = (const float*)d_in[13];
  const float* lng  = (const float*)d_in[14];
  const float* lnb  = (const float*)d_in[15];
  float* out = (float*)d_out;

  // ws (256 MiB): y1 [0,128Mi) interleaved, y2 [128Mi,256Mi) interleaved.
  // After conv2, region0 reused: f0 [0,32Mi) channel-major,
  // out_acc [32Mi,+14.05MB), wbf [64Mi,+41.9MB).
  // d_out scratch (dead before k_final): stats [0,6336), packed conv weights
  // wp2 at float ofs 8192 (7168 shorts), wp3 at 12288 (14336 shorts).
  char* ws = (char*)d_ws;
  unsigned short* y1u = (unsigned short*)ws;
  unsigned short* y2u = (unsigned short*)(ws + 134217728);
  bf16*  f0      = (bf16*)ws;
  float* out_acc = (float*)(ws + 33554432);
  unsigned short* wbf = (unsigned short*)(ws + 67108864);
  float* stats   = (float*)d_out;
  float* psum1 = stats;        float* psum2 = stats+2048; float* psum3 = stats+4096;
  float* scsh1 = stats+6144;   float* scsh2 = stats+6208; float* scsh3 = stats+6272;
  unsigned short* wp2 = (unsigned short*)(stats + 8192);
  unsigned short* wp3 = (unsigned short*)(stats + 12288);

  hipMemsetAsync(stats, 0, 6144*sizeof(float), stream);

  k_conv1<<<16384, 256, 0, stream>>>(x, w1, y1u);
  k_packw<<<84, 256, 0, stream>>>(w2, w3, wp2, wp3);
  k_stats1<<<2048, 256, 0, stream>>>(y1u, psum1);
  k_finalize<<<1, 64, 0, stream>>>(psum1, g1, b1, scsh1, 16, 1.f/4194304.f);
  k_conv2<<<8192, 256, 0, stream>>>(y1u, wp2, scsh1, y2u, psum2);
  k_finalize<<<1, 64, 0, stream>>>(psum2, g2, b2, scsh2, 16, 1.f/4194304.f);
  k_conv3<<<4096, 256, 0, stream>>>(y2u, wp3, scsh2, f0, psum3);
  k_finalize<<<1, 64, 0, stream>>>(psum3, g3, b3, scsh3, 32, 1.f/524288.f);
  k_cvtw<<<20480, 256, 0, stream>>>(tokw, auxw, wbf);
  k_gemm<<<352, 256, 0, stream>>>(f0, wbf, scsh3, out_acc);
  k_final<<<686, 256, 0, stream>>>(out_acc, tokb, auxb, lng, lnb, out);
}